// Round 7
// baseline (191.139 us; speedup 1.0000x reference)
//
#include <hip/hip_runtime.h>

// y[e, o] = sum_i weight[widx[e]][o][i] * values[iidx[e]][i]
// E = 1e6, N_W = 1024, D_IN = D_OUT = 16, fp32.
//
// R1: weight gather latency-bound -> 137 us kernel.
// R2: global-atomic scatter serialized -> 203 us.
// R3/R5: compiler refuses to keep 64-reg W resident (VGPR=48).
// R6: W in LDS, 4 lanes/conn -> 3.1M bank conflicts (4 addrs @ 256B stride),
//     16 ds_read_b128/conn in-loop (~30 us), 4x16B partial-line out stores
//     inflated WRITE 63->87 MB. mv = 58 us.
// R7: 16 lanes/conn, lane i owns OUTPUT ROW i:
//     - per-lane W = one row = 16 VGPRs (from LDS once; trivially resident)
//     - zero LDS reads in loop, zero conflicts, no shuffles
//     - out store = ONE instr per conn, full contiguous 64B line
//     - x: 4xb128, subgroup-shared addrs merge to 1 line/conn
//     - unroll 2 for MLP
//     Also: scan_per_bin 1024-block strided -> coalesced serial-per-bin.

#define D 16
#define NWMAX 1024
#define NB 256      // sort chunks
#define BTS 1024    // sort-phase threads per block
#define SEG 4

// ---------------- fallback naive kernel (R1, 137us) ----------------
__global__ __launch_bounds__(256) void linear_gather_mv(
    const float* __restrict__ values, const float* __restrict__ weight,
    const int* __restrict__ input_idx, const int* __restrict__ weight_idx,
    float* __restrict__ out, int E)
{
    int tid = blockIdx.x * blockDim.x + threadIdx.x;
    int e = tid >> 2;
    int j = tid & 3;
    if (e >= E) return;
    int ii = input_idx[e];
    int wi = weight_idx[e];
    const float4* xp = (const float4*)(values + (long long)ii * D);
    float4 x0 = xp[0], x1 = xp[1], x2 = xp[2], x3 = xp[3];
    const float4* wp = (const float4*)(weight + (long long)wi * (D * D) + j * (4 * D));
    float4 acc;
    float* accp = (float*)&acc;
    #pragma unroll
    for (int r = 0; r < 4; ++r) {
        float4 w0 = wp[r * 4 + 0], w1 = wp[r * 4 + 1], w2 = wp[r * 4 + 2], w3 = wp[r * 4 + 3];
        accp[r] = w0.x * x0.x + w0.y * x0.y + w0.z * x0.z + w0.w * x0.w
                + w1.x * x1.x + w1.y * x1.y + w1.z * x1.z + w1.w * x1.w
                + w2.x * x2.x + w2.y * x2.y + w2.z * x2.z + w2.w * x2.w
                + w3.x * x3.x + w3.y * x3.y + w3.z * x3.z + w3.w * x3.w;
    }
    ((float4*)out)[(long long)e * 4 + j] = acc;
}

// ---------------- phase 1: per-block private histograms ----------------
__global__ __launch_bounds__(BTS) void hist_blocks(
    const int* __restrict__ widx, int E, int chunk,
    int* __restrict__ hist2d, int NW)
{
    __shared__ int lh[NWMAX];
    for (int i = threadIdx.x; i < NW; i += BTS) lh[i] = 0;
    __syncthreads();
    int s0 = blockIdx.x * chunk;
    int s1 = min(E, s0 + chunk);
    for (int e = s0 + threadIdx.x; e < s1; e += BTS)
        atomicAdd(&lh[widx[e]], 1);
    __syncthreads();
    int* row = hist2d + (long long)blockIdx.x * NW;
    for (int i = threadIdx.x; i < NW; i += BTS) row[i] = lh[i];
}

// -- phase 2a: per-bin serial exclusive scan across blocks (coalesced) --
// thread b owns bin b; loop over the NB chunk counts. Consecutive threads
// touch consecutive addresses -> fully coalesced (old version strided 4KB).
__global__ __launch_bounds__(256) void scan_per_bin_serial(
    int* __restrict__ hist2d, int* __restrict__ total, int NW)
{
    int b = blockIdx.x * blockDim.x + threadIdx.x;
    if (b >= NW) return;
    int run = 0;
    for (int t = 0; t < NB; ++t) {
        long long idx = (long long)t * NW + b;
        int v = hist2d[idx];
        hist2d[idx] = run;       // exclusive prefix for (bin, block)
        run += v;
    }
    total[b] = run;
}

// ---------------- phase 2b: scan over bins -> bucket offsets ----------------
__global__ __launch_bounds__(1024) void scan_bins(
    const int* __restrict__ total, int* __restrict__ offsets, int NW)
{
    __shared__ int buf[2 * NWMAX];
    int t = threadIdx.x;
    int v = (t < NW) ? total[t] : 0;
    buf[t] = v;
    __syncthreads();
    int pin = 0;
    for (int off = 1; off < NWMAX; off <<= 1) {
        int x = buf[pin * NWMAX + t];
        if (t >= off) x += buf[pin * NWMAX + t - off];
        buf[(1 - pin) * NWMAX + t] = x;
        pin = 1 - pin;
        __syncthreads();
    }
    int incl = buf[pin * NWMAX + t];
    if (t < NW) {
        offsets[t + 1] = incl;
        if (t == 0) offsets[0] = 0;
    }
}

// ---------------- phase 3: deterministic scatter, LDS cursors ----------------
__global__ __launch_bounds__(BTS) void scatter_det(
    const int* __restrict__ widx, const int* __restrict__ iidx, int E, int chunk,
    const int* __restrict__ hist2d, const int* __restrict__ offsets,
    int2* __restrict__ perm, int NW)
{
    __shared__ int cur[NWMAX];
    int p = blockIdx.x;
    const int* row = hist2d + (long long)p * NW;
    for (int i = threadIdx.x; i < NW; i += BTS)
        cur[i] = offsets[i] + row[i];
    __syncthreads();
    int s0 = p * chunk;
    int s1 = min(E, s0 + chunk);
    for (int e = s0 + threadIdx.x; e < s1; e += BTS) {
        int wi = widx[e];
        int pos = atomicAdd(&cur[wi], 1);
        perm[pos] = make_int2(e, iidx[e]);
    }
}

// ---- phase 4: 16 lanes/conn, lane i = output row i; W row in 16 VGPRs ----
__global__ __launch_bounds__(256, 4) void bucket_mv(
    const float* __restrict__ values, const float* __restrict__ weight,
    const int* __restrict__ offsets, const int2* __restrict__ perm,
    float* __restrict__ out)
{
    __shared__ float Wl[D * D];
    int b = blockIdx.x;
    Wl[threadIdx.x] = weight[(long long)b * (D * D) + threadIdx.x];

    int lo = offsets[b], hi = offsets[b + 1];
    int cnt = hi - lo;
    __syncthreads();
    if (cnt == 0) return;
    int per = (cnt + SEG - 1) / SEG;
    int s0 = lo + blockIdx.y * per;
    int s1 = min(hi, s0 + per);
    if (s0 >= s1) return;

    int i  = threadIdx.x & 15;   // output row this lane owns
    int sg = threadIdx.x >> 4;   // subgroup (0..15), one conn pair per iter

    // my W row, 16 VGPRs — loaded once, loop-invariant
    const float4* wr = (const float4*)(Wl + i * D);
    float4 w0 = wr[0], w1 = wr[1], w2 = wr[2], w3 = wr[3];

    for (int k = s0 + 2 * sg; k < s1; k += 512 / D) {   // 32 conns per block-iter
        int k1 = k + 1;
        bool hB = (k1 < s1);
        int2 pA = perm[k];                 // 16 lanes same addr -> broadcast
        int2 pB = hB ? perm[k1] : pA;

        // two independent x chains; addresses shared within subgroup -> merged
        const float4* xa = (const float4*)(values + (long long)pA.y * D);
        const float4* xb = (const float4*)(values + (long long)pB.y * D);
        float4 a0 = xa[0], a1 = xa[1], a2 = xa[2], a3 = xa[3];
        float4 b0 = xb[0], b1 = xb[1], b2 = xb[2], b3 = xb[3];

        float ya = w0.x*a0.x + w0.y*a0.y + w0.z*a0.z + w0.w*a0.w
                 + w1.x*a1.x + w1.y*a1.y + w1.z*a1.z + w1.w*a1.w
                 + w2.x*a2.x + w2.y*a2.y + w2.z*a2.z + w2.w*a2.w
                 + w3.x*a3.x + w3.y*a3.y + w3.z*a3.z + w3.w*a3.w;
        out[(long long)pA.x * D + i] = ya;   // 16 lanes -> one full 64B line

        if (hB) {
            float yb = w0.x*b0.x + w0.y*b0.y + w0.z*b0.z + w0.w*b0.w
                     + w1.x*b1.x + w1.y*b1.y + w1.z*b1.z + w1.w*b1.w
                     + w2.x*b2.x + w2.y*b2.y + w2.z*b2.z + w2.w*b2.w
                     + w3.x*b3.x + w3.y*b3.y + w3.z*b3.z + w3.w*b3.w;
            out[(long long)pB.x * D + i] = yb;
        }
    }
}

extern "C" void kernel_launch(void* const* d_in, const int* in_sizes, int n_in,
                              void* d_out, int out_size, void* d_ws, size_t ws_size,
                              hipStream_t stream) {
    const float* values     = (const float*)d_in[0];
    const float* weight     = (const float*)d_in[1];
    const int*   input_idx  = (const int*)d_in[2];
    const int*   weight_idx = (const int*)d_in[3];
    float*       out        = (float*)d_out;

    int E  = in_sizes[2];
    int NW = in_sizes[1] / (D * D);
    int chunk = (E + NB - 1) / NB;

    // workspace: hist2d[NB*NW] | total[NW] | offsets[NW+1] | pad | perm[2E]
    size_t n_hist = (size_t)NB * NW;
    size_t n_head = n_hist + NW + NW + 1;
    n_head = (n_head + 1) & ~(size_t)1;
    size_t need = (n_head + 2 * (size_t)E) * sizeof(int);

    if (NW > NWMAX || ws_size < need) {
        int total_thr = E * 4;
        int grid = (total_thr + 255) / 256;
        hipLaunchKernelGGL(linear_gather_mv, dim3(grid), dim3(256), 0, stream,
                           values, weight, input_idx, weight_idx, out, E);
        return;
    }

    int* hist2d  = (int*)d_ws;
    int* total   = hist2d + n_hist;
    int* offsets = total + NW;
    int2* perm   = (int2*)((int*)d_ws + n_head);

    hipLaunchKernelGGL(hist_blocks, dim3(NB), dim3(BTS), 0, stream,
                       weight_idx, E, chunk, hist2d, NW);
    hipLaunchKernelGGL(scan_per_bin_serial, dim3((NW + 255) / 256), dim3(256), 0, stream,
                       hist2d, total, NW);
    hipLaunchKernelGGL(scan_bins, dim3(1), dim3(1024), 0, stream,
                       total, offsets, NW);
    hipLaunchKernelGGL(scatter_det, dim3(NB), dim3(BTS), 0, stream,
                       weight_idx, input_idx, E, chunk, hist2d, offsets, perm, NW);
    hipLaunchKernelGGL(bucket_mv, dim3(NW, SEG), dim3(256), 0, stream,
                       values, weight, offsets, perm, out);
}

// Round 8
// 166.409 us; speedup vs baseline: 1.1486x; 1.1486x over previous
//
#include <hip/hip_runtime.h>

// y[e, o] = sum_i weight[widx[e]][o][i] * values[iidx[e]][i]
// E = 1e6, N_W = 1024, D_IN = D_OUT = 16, fp32.
//
// R1: weight gather latency-bound -> 137 us kernel.
// R2: global-atomic scatter serialized -> 203 us.
// R3/R5: compiler refuses to keep W resident (VGPR=48, re-fetch per iter).
// R6: W in LDS, 4 lanes/conn -> 3.1M bank conflicts, mv 58 us.
// R7: 16 lanes/conn (full-line store ok, WRITE 64MB exact) BUT VGPR=24:
//     machine-sinking pushed the W loads back into the loop (8 ds_read/iter);
//     serial scan_per_bin ran on 4 blocks -> sort-phase regression.
// R8: - W row pinned in 16 VGPRs via empty asm volatile "+v" barrier after
//       the LDS load: compiler cannot rematerialize, loop has ZERO ds_reads.
//     - 4-way unroll: 4 independent perm->x chains per subgroup.
//     - scan_per_bin restored to parallel (NW blocks x NB threads).

#define D 16
#define NWMAX 1024
#define NB 256      // sort chunks
#define BTS 1024    // sort-phase threads per block
#define SEG 4

// ---------------- fallback naive kernel (R1, 137us) ----------------
__global__ __launch_bounds__(256) void linear_gather_mv(
    const float* __restrict__ values, const float* __restrict__ weight,
    const int* __restrict__ input_idx, const int* __restrict__ weight_idx,
    float* __restrict__ out, int E)
{
    int tid = blockIdx.x * blockDim.x + threadIdx.x;
    int e = tid >> 2;
    int j = tid & 3;
    if (e >= E) return;
    int ii = input_idx[e];
    int wi = weight_idx[e];
    const float4* xp = (const float4*)(values + (long long)ii * D);
    float4 x0 = xp[0], x1 = xp[1], x2 = xp[2], x3 = xp[3];
    const float4* wp = (const float4*)(weight + (long long)wi * (D * D) + j * (4 * D));
    float4 acc;
    float* accp = (float*)&acc;
    #pragma unroll
    for (int r = 0; r < 4; ++r) {
        float4 w0 = wp[r * 4 + 0], w1 = wp[r * 4 + 1], w2 = wp[r * 4 + 2], w3 = wp[r * 4 + 3];
        accp[r] = w0.x * x0.x + w0.y * x0.y + w0.z * x0.z + w0.w * x0.w
                + w1.x * x1.x + w1.y * x1.y + w1.z * x1.z + w1.w * x1.w
                + w2.x * x2.x + w2.y * x2.y + w2.z * x2.z + w2.w * x2.w
                + w3.x * x3.x + w3.y * x3.y + w3.z * x3.z + w3.w * x3.w;
    }
    ((float4*)out)[(long long)e * 4 + j] = acc;
}

// ---------------- phase 1: per-block private histograms ----------------
__global__ __launch_bounds__(BTS) void hist_blocks(
    const int* __restrict__ widx, int E, int chunk,
    int* __restrict__ hist2d, int NW)
{
    __shared__ int lh[NWMAX];
    for (int i = threadIdx.x; i < NW; i += BTS) lh[i] = 0;
    __syncthreads();
    int s0 = blockIdx.x * chunk;
    int s1 = min(E, s0 + chunk);
    for (int e = s0 + threadIdx.x; e < s1; e += BTS)
        atomicAdd(&lh[widx[e]], 1);
    __syncthreads();
    int* row = hist2d + (long long)blockIdx.x * NW;
    for (int i = threadIdx.x; i < NW; i += BTS) row[i] = lh[i];
}

// ------- phase 2a: per-bin exclusive scan across blocks (parallel) -------
__global__ __launch_bounds__(NB) void scan_per_bin(
    int* __restrict__ hist2d, int* __restrict__ total, int NW)
{
    __shared__ int buf[2 * NB];
    int b = blockIdx.x;   // bin
    int t = threadIdx.x;  // sort-block index
    int v = hist2d[(long long)t * NW + b];
    buf[t] = v;
    __syncthreads();
    int pin = 0;
    for (int off = 1; off < NB; off <<= 1) {
        int x = buf[pin * NB + t];
        if (t >= off) x += buf[pin * NB + t - off];
        buf[(1 - pin) * NB + t] = x;
        pin = 1 - pin;
        __syncthreads();
    }
    int incl = buf[pin * NB + t];
    hist2d[(long long)t * NW + b] = incl - v;
    if (t == NB - 1) total[b] = incl;
}

// ---------------- phase 2b: scan over bins -> bucket offsets ----------------
__global__ __launch_bounds__(1024) void scan_bins(
    const int* __restrict__ total, int* __restrict__ offsets, int NW)
{
    __shared__ int buf[2 * NWMAX];
    int t = threadIdx.x;
    int v = (t < NW) ? total[t] : 0;
    buf[t] = v;
    __syncthreads();
    int pin = 0;
    for (int off = 1; off < NWMAX; off <<= 1) {
        int x = buf[pin * NWMAX + t];
        if (t >= off) x += buf[pin * NWMAX + t - off];
        buf[(1 - pin) * NWMAX + t] = x;
        pin = 1 - pin;
        __syncthreads();
    }
    int incl = buf[pin * NWMAX + t];
    if (t < NW) {
        offsets[t + 1] = incl;
        if (t == 0) offsets[0] = 0;
    }
}

// ---------------- phase 3: deterministic scatter, LDS cursors ----------------
__global__ __launch_bounds__(BTS) void scatter_det(
    const int* __restrict__ widx, const int* __restrict__ iidx, int E, int chunk,
    const int* __restrict__ hist2d, const int* __restrict__ offsets,
    int2* __restrict__ perm, int NW)
{
    __shared__ int cur[NWMAX];
    int p = blockIdx.x;
    const int* row = hist2d + (long long)p * NW;
    for (int i = threadIdx.x; i < NW; i += BTS)
        cur[i] = offsets[i] + row[i];
    __syncthreads();
    int s0 = p * chunk;
    int s1 = min(E, s0 + chunk);
    for (int e = s0 + threadIdx.x; e < s1; e += BTS) {
        int wi = widx[e];
        int pos = atomicAdd(&cur[wi], 1);
        perm[pos] = make_int2(e, iidx[e]);
    }
}

#define ROWDOT(X0, X1, X2, X3)                                   \
    (w0.x*X0.x + w0.y*X0.y + w0.z*X0.z + w0.w*X0.w               \
   + w1.x*X1.x + w1.y*X1.y + w1.z*X1.z + w1.w*X1.w               \
   + w2.x*X2.x + w2.y*X2.y + w2.z*X2.z + w2.w*X2.w               \
   + w3.x*X3.x + w3.y*X3.y + w3.z*X3.z + w3.w*X3.w)

// ---- phase 4: 16 lanes/conn, lane i = output row i; W row PINNED in
// 16 VGPRs via asm barrier (compiler cannot sink/remat the LDS loads).
__global__ __launch_bounds__(256, 4) void bucket_mv(
    const float* __restrict__ values, const float* __restrict__ weight,
    const int* __restrict__ offsets, const int2* __restrict__ perm,
    float* __restrict__ out)
{
    __shared__ float Wl[D * D];
    int b = blockIdx.x;
    Wl[threadIdx.x] = weight[(long long)b * (D * D) + threadIdx.x];

    int lo = offsets[b], hi = offsets[b + 1];
    int cnt = hi - lo;
    __syncthreads();
    if (cnt == 0) return;
    int per = (cnt + SEG - 1) / SEG;
    int s0 = lo + blockIdx.y * per;
    int s1 = min(hi, s0 + per);
    if (s0 >= s1) return;

    int i  = threadIdx.x & 15;   // output row this lane owns
    int sg = threadIdx.x >> 4;   // subgroup (0..15)

    // my W row -> 16 VGPRs, then opaque barrier: cannot be sunk or re-read
    const float4* wr = (const float4*)(Wl + i * D);
    float4 w0 = wr[0], w1 = wr[1], w2 = wr[2], w3 = wr[3];
    asm volatile("" : "+v"(w0.x), "+v"(w0.y), "+v"(w0.z), "+v"(w0.w),
                      "+v"(w1.x), "+v"(w1.y), "+v"(w1.z), "+v"(w1.w),
                      "+v"(w2.x), "+v"(w2.y), "+v"(w2.z), "+v"(w2.w),
                      "+v"(w3.x), "+v"(w3.y), "+v"(w3.z), "+v"(w3.w));

    // subgroup handles 4 contiguous conns per iter; block covers 64/iter
    for (int k0 = s0 + 4 * sg; k0 < s1; k0 += 64) {
        int k1 = k0 + 1, k2 = k0 + 2, k3 = k0 + 3;
        bool h1 = k1 < s1, h2 = k2 < s1, h3 = k3 < s1;
        int2 pA = perm[k0];
        int2 pB = h1 ? perm[k1] : pA;
        int2 pC = h2 ? perm[k2] : pA;
        int2 pD = h3 ? perm[k3] : pA;

        // 4 independent gather chains (vm loads all issue before first use)
        const float4* xa = (const float4*)(values + (long long)pA.y * D);
        const float4* xb = (const float4*)(values + (long long)pB.y * D);
        const float4* xc = (const float4*)(values + (long long)pC.y * D);
        const float4* xd = (const float4*)(values + (long long)pD.y * D);
        float4 a0 = xa[0], a1 = xa[1], a2 = xa[2], a3 = xa[3];
        float4 b0 = xb[0], b1 = xb[1], b2 = xb[2], b3 = xb[3];
        float4 c0 = xc[0], c1 = xc[1], c2 = xc[2], c3 = xc[3];
        float4 d0 = xd[0], d1 = xd[1], d2 = xd[2], d3 = xd[3];

        out[(long long)pA.x * D + i] = ROWDOT(a0, a1, a2, a3);
        if (h1) out[(long long)pB.x * D + i] = ROWDOT(b0, b1, b2, b3);
        if (h2) out[(long long)pC.x * D + i] = ROWDOT(c0, c1, c2, c3);
        if (h3) out[(long long)pD.x * D + i] = ROWDOT(d0, d1, d2, d3);
    }
}

extern "C" void kernel_launch(void* const* d_in, const int* in_sizes, int n_in,
                              void* d_out, int out_size, void* d_ws, size_t ws_size,
                              hipStream_t stream) {
    const float* values     = (const float*)d_in[0];
    const float* weight     = (const float*)d_in[1];
    const int*   input_idx  = (const int*)d_in[2];
    const int*   weight_idx = (const int*)d_in[3];
    float*       out        = (float*)d_out;

    int E  = in_sizes[2];
    int NW = in_sizes[1] / (D * D);
    int chunk = (E + NB - 1) / NB;

    // workspace: hist2d[NB*NW] | total[NW] | offsets[NW+1] | pad | perm[2E]
    size_t n_hist = (size_t)NB * NW;
    size_t n_head = n_hist + NW + NW + 1;
    n_head = (n_head + 1) & ~(size_t)1;
    size_t need = (n_head + 2 * (size_t)E) * sizeof(int);

    if (NW > NWMAX || ws_size < need) {
        int total_thr = E * 4;
        int grid = (total_thr + 255) / 256;
        hipLaunchKernelGGL(linear_gather_mv, dim3(grid), dim3(256), 0, stream,
                           values, weight, input_idx, weight_idx, out, E);
        return;
    }

    int* hist2d  = (int*)d_ws;
    int* total   = hist2d + n_hist;
    int* offsets = total + NW;
    int2* perm   = (int2*)((int*)d_ws + n_head);

    hipLaunchKernelGGL(hist_blocks, dim3(NB), dim3(BTS), 0, stream,
                       weight_idx, E, chunk, hist2d, NW);
    hipLaunchKernelGGL(scan_per_bin, dim3(NW), dim3(NB), 0, stream,
                       hist2d, total, NW);
    hipLaunchKernelGGL(scan_bins, dim3(1), dim3(1024), 0, stream,
                       total, offsets, NW);
    hipLaunchKernelGGL(scatter_det, dim3(NB), dim3(BTS), 0, stream,
                       weight_idx, input_idx, E, chunk, hist2d, offsets, perm, NW);
    hipLaunchKernelGGL(bucket_mv, dim3(NW, SEG), dim3(256), 0, stream,
                       values, weight, offsets, perm, out);
}